// Round 9
// baseline (1457.838 us; speedup 1.0000x reference)
//
#include <hip/hip_runtime.h>

// GraphSAGE on MI355X.
// adj is 0.001-dense (avg degree ~16). One 1.07 GB scan of adj (the roofline)
// scatters edges DIRECTLY into per-target slot lists (atomicAdd on deg returns
// the slot index). Then 3 fused layers: sparse mean-agg + fp32 dense GEMM.
// R2: pre-transposed Wt (coalesced W streams). R6: 32 nodes/block, NPT=4
// (wave's 128KB Wt stream serves 8 nodes). R7: direct-slot scatter.
// R8: software-pipelined k_count. R9: gather = whole-wave-per-node (64 lanes
// = 2 edges x 32 float4, wave-uniform trip count) — removes the intra-wave
// Poisson max imbalance (E[max of 8 Pois(16)]~25 vs mean 16, ~1.5x slack).

#define NN 16384          // nodes
#define SLOTC 64          // per-target slot capacity (deg~Pois(16.4); P(>64)~1e-19)

typedef int iv4 __attribute__((ext_vector_type(4)));   // native vector for ntload

// ---- workspace layout (bytes) ----
#define OFF_DEG   0u
#define OFF_SLOT  65536u                               // int[16384*64] = 4 MB
#define OFF_WT0   (65536u + 4194304u)                  // 4259840
#define OFF_WT1   (OFF_WT0 + 131072u)                  // Wt0 [256][128] f32
#define OFF_WT2   (OFF_WT1 + 131072u)                  // Wt1 [256][128] f32
#define OFF_H1    (OFF_WT2 + 65536u)                   // Wt2 [256][64] f32
#define OFF_H2    (OFF_H1 + 4u * NN * 128u)

// ---------- kernel 0: transpose [Wl;Wr] -> Wt[256][FOUT]; zero deg ----------
__global__ void k_wt(const float* __restrict__ Wl0, const float* __restrict__ Wr0,
                     const float* __restrict__ Wl1, const float* __restrict__ Wr1,
                     const float* __restrict__ Wl2, const float* __restrict__ Wr2,
                     float* __restrict__ wt0, float* __restrict__ wt1,
                     float* __restrict__ wt2, int* __restrict__ deg) {
    int g = blockIdx.x * 256 + threadIdx.x;
    if (g < NN) deg[g] = 0;            // runs before k_count on the stream
    if (g < 32768) {
        int k = g >> 7, o = g & 127;
        wt0[g] = (k < 128) ? Wl0[o * 128 + k] : Wr0[o * 128 + (k - 128)];
    } else if (g < 65536) {
        int gg = g - 32768;
        int k = gg >> 7, o = gg & 127;
        wt1[gg] = (k < 128) ? Wl1[o * 128 + k] : Wr1[o * 128 + (k - 128)];
    } else if (g < 81920) {
        int gg = g - 65536;
        int k = gg >> 6, o = gg & 63;
        wt2[gg] = (k < 128) ? Wl2[o * 128 + k] : Wr2[o * 128 + (k - 128)];
    }
}

// ---------- kernel 1: scan adj once, scatter edges into slot lists ----------
__device__ __forceinline__ void emit_hits(iv4 v, int idx4, int* __restrict__ deg,
                                          int* __restrict__ slots) {
    if ((v.x | v.y | v.z | v.w) == 0) return;   // fp 0.0f is all-zero bits
    int base = idx4 << 2;
    int s = base >> 14;            // row (source)
    int t = base & (NN - 1);       // col (target)
    int w[4] = {v.x, v.y, v.z, v.w};
    #pragma unroll
    for (int k = 0; k < 4; ++k) {
        if (w[k] != 0) {
            int pos = atomicAdd(&deg[t + k], 1);   // returns slot index
            if (pos < SLOTC) slots[(t + k) * SLOTC + pos] = s;
        }
    }
}

// Explicit software pipeline: loads for iter n+1 are issued BEFORE the branchy
// emit of iter n, so the wave waits vmcnt(2), not vmcnt(0) -> latency overlap.
__global__ __launch_bounds__(256) void k_count(
    const iv4* __restrict__ adj4, int* __restrict__ deg,
    int* __restrict__ slots) {
    const int stride = 2048 * 256;         // 2^19; total4 = 2^26 = 128 strides
    int i = blockIdx.x * 256 + threadIdx.x;
    iv4 a = __builtin_nontemporal_load(&adj4[i]);
    iv4 b = __builtin_nontemporal_load(&adj4[i + stride]);
    #pragma unroll 1
    for (int n = 0; n < 63; ++n) {
        iv4 c = __builtin_nontemporal_load(&adj4[i + 2 * stride]);
        iv4 d = __builtin_nontemporal_load(&adj4[i + 3 * stride]);
        emit_hits(a, i, deg, slots);
        emit_hits(b, i + stride, deg, slots);
        a = c; b = d; i += 2 * stride;
    }
    emit_hits(a, i, deg, slots);
    emit_hits(b, i + stride, deg, slots);
}

// ---------- kernel 2: fused SAGE layer (mean-agg + Wt GEMM + bias (+ReLU)) ----
// 32 nodes/block, 512 blocks. Gather: whole wave per node (8 nodes/wave,
// sequential): 64 lanes = 2 edges x 32 float4 -> two full 512B rows per iter,
// coalesced, wave-uniform trip count (no cluster imbalance); halves combined
// via shfl_xor(32). GEMM: NPT=4 -> wave's 128KB Wt stream serves 8 nodes.
// LDS z[32][264] floats: float4 slots [0,32)=agg, [32,64)=self, 2 pad.
template <int FOUT, bool RELU>
__global__ __launch_bounds__(256) void k_layer(
    const float4* __restrict__ hin,    // [NN][32] float4
    float* __restrict__ hout,          // [NN][FOUT]
    const int* __restrict__ slots, const int* __restrict__ deg,
    const float4* __restrict__ Wt4,    // [256][FOUT/4]
    const float* __restrict__ bias)    // [FOUT]
{
    constexpr int S4 = 66;             // float4 stride per node row
    __shared__ float4 z[32 * S4];
    const int tid = threadIdx.x;
    const int nodeBase = blockIdx.x * 32;

    // stage self rows: 1024 float4s, coalesced (32 consecutive tids = one row)
    #pragma unroll
    for (int r = 0; r < 4; ++r) {
        int g = tid + 256 * r;
        int n = g >> 5, j = g & 31;
        z[n * S4 + 32 + j] = hin[(nodeBase + n) * 32 + j];
    }

    // mean aggregation: whole wave per node, 8 nodes sequentially per wave.
    {
        const int wave = tid >> 6;     // 0..3
        const int lane = tid & 63;
        const int half = lane >> 5;    // 0/1: which of 2 edges this iter
        const int col = lane & 31;     // float4 column within row
        #pragma unroll 1
        for (int nn = 0; nn < 8; ++nn) {
            const int nl = wave * 8 + nn;
            const int node = nodeBase + nl;
            const int d = deg[node];               // wave-uniform
            const int dc = d < SLOTC ? d : SLOTC;
            const int* el = slots + node * SLOTC;
            float4 acc = make_float4(0.f, 0.f, 0.f, 0.f);
            int e = 0;
            for (; e + 4 <= dc; e += 4) {          // 4 edges per iter (2/half)
                int sA = el[e + half];
                int sB = el[e + 2 + half];
                float4 vA = hin[sA * 32 + col];
                float4 vB = hin[sB * 32 + col];
                acc.x += vA.x + vB.x; acc.y += vA.y + vB.y;
                acc.z += vA.z + vB.z; acc.w += vA.w + vB.w;
            }
            for (; e < dc; e += 2) {               // 0..3 leftover edges
                if (e + half < dc) {
                    float4 v = hin[el[e + half] * 32 + col];
                    acc.x += v.x; acc.y += v.y; acc.z += v.z; acc.w += v.w;
                }
            }
            // combine the two halves (xor-32 butterfly), both end with full sum
            acc.x += __shfl_xor(acc.x, 32);
            acc.y += __shfl_xor(acc.y, 32);
            acc.z += __shfl_xor(acc.z, 32);
            acc.w += __shfl_xor(acc.w, 32);
            if (half == 0) {
                const float di = d > 0 ? 1.0f / (float)d : 0.0f;
                acc.x *= di; acc.y *= di; acc.z *= di; acc.w *= di;
                z[nl * S4 + col] = acc;
            }
        }
    }
    __syncthreads();

    // GEMM: out[32 x FOUT] = [agg|self][32 x 256] @ Wt + b
    constexpr int TO = FOUT / 4;       // 32 or 16
    constexpr int TN = 256 / TO;       // 8 or 16
    constexpr int NPT = 32 / TN;       // 4 or 2
    const int to = tid % TO;
    const int tn = tid / TO;

    float4 acc[NPT];
    #pragma unroll
    for (int m = 0; m < NPT; ++m) acc[m] = make_float4(0.f, 0.f, 0.f, 0.f);

    #pragma unroll 2
    for (int k4 = 0; k4 < 64; ++k4) {
        // Wt rows 4k4..4k4+3 at float4-col `to`: contiguous across lanes
        float4 w0 = Wt4[(4 * k4 + 0) * TO + to];
        float4 w1 = Wt4[(4 * k4 + 1) * TO + to];
        float4 w2 = Wt4[(4 * k4 + 2) * TO + to];
        float4 w3 = Wt4[(4 * k4 + 3) * TO + to];
        #pragma unroll
        for (int m = 0; m < NPT; ++m) {
            float4 a = z[(tn * NPT + m) * S4 + k4];   // ks 4k4..4k4+3
            acc[m].x += a.x * w0.x + a.y * w1.x + a.z * w2.x + a.w * w3.x;
            acc[m].y += a.x * w0.y + a.y * w1.y + a.z * w2.y + a.w * w3.y;
            acc[m].z += a.x * w0.z + a.y * w1.z + a.z * w2.z + a.w * w3.z;
            acc[m].w += a.x * w0.w + a.y * w1.w + a.z * w2.w + a.w * w3.w;
        }
    }

    // epilogue: +bias, optional ReLU, coalesced float4 store
    const float4 bb = ((const float4*)bias)[to];
    #pragma unroll
    for (int m = 0; m < NPT; ++m) {
        float4 o;
        o.x = acc[m].x + bb.x; o.y = acc[m].y + bb.y;
        o.z = acc[m].z + bb.z; o.w = acc[m].w + bb.w;
        if (RELU) {
            o.x = fmaxf(o.x, 0.f); o.y = fmaxf(o.y, 0.f);
            o.z = fmaxf(o.z, 0.f); o.w = fmaxf(o.w, 0.f);
        }
        ((float4*)hout)[(nodeBase + tn * NPT + m) * TO + to] = o;
    }
}

extern "C" void kernel_launch(void* const* d_in, const int* in_sizes, int n_in,
                              void* d_out, int out_size, void* d_ws, size_t ws_size,
                              hipStream_t stream) {
    const float* x = (const float*)d_in[0];
    const iv4* adj4 = (const iv4*)d_in[1];
    const float* Wl0 = (const float*)d_in[2];
    const float* b0 = (const float*)d_in[3];
    const float* Wr0 = (const float*)d_in[4];
    const float* Wl1 = (const float*)d_in[5];
    const float* b1 = (const float*)d_in[6];
    const float* Wr1 = (const float*)d_in[7];
    const float* Wl2 = (const float*)d_in[8];
    const float* b2 = (const float*)d_in[9];
    const float* Wr2 = (const float*)d_in[10];

    char* ws = (char*)d_ws;
    int* deg = (int*)(ws + OFF_DEG);
    int* slots = (int*)(ws + OFF_SLOT);
    float* wt0 = (float*)(ws + OFF_WT0);
    float* wt1 = (float*)(ws + OFF_WT1);
    float* wt2 = (float*)(ws + OFF_WT2);
    float* h1 = (float*)(ws + OFF_H1);
    float* h2 = (float*)(ws + OFF_H2);

    // 0) transpose weights + zero deg (precedes k_count on this stream)
    k_wt<<<320, 256, 0, stream>>>(Wl0, Wr0, Wl1, Wr1, Wl2, Wr2,
                                  wt0, wt1, wt2, deg);
    // 1) scan adj (the 1.07 GB roofline read), scatter edges into slots
    k_count<<<2048, 256, 0, stream>>>(adj4, deg, slots);
    // 2) three fused SAGE layers
    k_layer<128, true><<<NN / 32, 256, 0, stream>>>(
        (const float4*)x, h1, slots, deg, (const float4*)wt0, b0);
    k_layer<128, true><<<NN / 32, 256, 0, stream>>>(
        (const float4*)h1, h2, slots, deg, (const float4*)wt1, b1);
    k_layer<64, false><<<NN / 32, 256, 0, stream>>>(
        (const float4*)h2, (float*)d_out, slots, deg, (const float4*)wt2, b2);
}

// Round 10
// 1445.410 us; speedup vs baseline: 1.0086x; 1.0086x over previous
//
#include <hip/hip_runtime.h>

// GraphSAGE on MI355X.
// adj is 0.001-dense (avg degree ~16). One 1.07 GB scan of adj (the roofline)
// scatters edges DIRECTLY into per-target slot lists (atomicAdd on deg returns
// the slot index). Then 3 fused layers: sparse mean-agg + fp32 dense GEMM.
// R2: pre-transposed Wt (coalesced W streams). R6: 32 nodes/block, NPT=4
// (wave's 128KB Wt stream serves 8 nodes). R7: direct-slot scatter.
// R8: software-pipelined k_count; cluster gather with int4 index loads +
//     4-row unroll (16 row loads in flight per lane)  -> 1415 us (best).
// R9 FAILED: whole-wave-per-node gather dropped in-flight loads 16->2/lane;
//     latency-bound loss (+43 us) swamped the Poisson-balance win. Reverted.

#define NN 16384          // nodes
#define SLOTC 64          // per-target slot capacity (deg~Pois(16.4); P(>64)~1e-19)

typedef int iv4 __attribute__((ext_vector_type(4)));   // native vector for ntload

// ---- workspace layout (bytes) ----
#define OFF_DEG   0u
#define OFF_SLOT  65536u                               // int[16384*64] = 4 MB
#define OFF_WT0   (65536u + 4194304u)                  // 4259840
#define OFF_WT1   (OFF_WT0 + 131072u)                  // Wt0 [256][128] f32
#define OFF_WT2   (OFF_WT1 + 131072u)                  // Wt1 [256][128] f32
#define OFF_H1    (OFF_WT2 + 65536u)                   // Wt2 [256][64] f32
#define OFF_H2    (OFF_H1 + 4u * NN * 128u)

// ---------- kernel 0: transpose [Wl;Wr] -> Wt[256][FOUT]; zero deg ----------
__global__ void k_wt(const float* __restrict__ Wl0, const float* __restrict__ Wr0,
                     const float* __restrict__ Wl1, const float* __restrict__ Wr1,
                     const float* __restrict__ Wl2, const float* __restrict__ Wr2,
                     float* __restrict__ wt0, float* __restrict__ wt1,
                     float* __restrict__ wt2, int* __restrict__ deg) {
    int g = blockIdx.x * 256 + threadIdx.x;
    if (g < NN) deg[g] = 0;            // runs before k_count on the stream
    if (g < 32768) {
        int k = g >> 7, o = g & 127;
        wt0[g] = (k < 128) ? Wl0[o * 128 + k] : Wr0[o * 128 + (k - 128)];
    } else if (g < 65536) {
        int gg = g - 32768;
        int k = gg >> 7, o = gg & 127;
        wt1[gg] = (k < 128) ? Wl1[o * 128 + k] : Wr1[o * 128 + (k - 128)];
    } else if (g < 81920) {
        int gg = g - 65536;
        int k = gg >> 6, o = gg & 63;
        wt2[gg] = (k < 128) ? Wl2[o * 128 + k] : Wr2[o * 128 + (k - 128)];
    }
}

// ---------- kernel 1: scan adj once, scatter edges into slot lists ----------
__device__ __forceinline__ void emit_hits(iv4 v, int idx4, int* __restrict__ deg,
                                          int* __restrict__ slots) {
    if ((v.x | v.y | v.z | v.w) == 0) return;   // fp 0.0f is all-zero bits
    int base = idx4 << 2;
    int s = base >> 14;            // row (source)
    int t = base & (NN - 1);       // col (target)
    int w[4] = {v.x, v.y, v.z, v.w};
    #pragma unroll
    for (int k = 0; k < 4; ++k) {
        if (w[k] != 0) {
            int pos = atomicAdd(&deg[t + k], 1);   // returns slot index
            if (pos < SLOTC) slots[(t + k) * SLOTC + pos] = s;
        }
    }
}

// Explicit software pipeline: loads for iter n+1 are issued BEFORE the branchy
// emit of iter n, so the wave waits vmcnt(2), not vmcnt(0) -> latency overlap.
__global__ __launch_bounds__(256) void k_count(
    const iv4* __restrict__ adj4, int* __restrict__ deg,
    int* __restrict__ slots) {
    const int stride = 2048 * 256;         // 2^19; total4 = 2^26 = 128 strides
    int i = blockIdx.x * 256 + threadIdx.x;
    iv4 a = __builtin_nontemporal_load(&adj4[i]);
    iv4 b = __builtin_nontemporal_load(&adj4[i + stride]);
    #pragma unroll 1
    for (int n = 0; n < 63; ++n) {
        iv4 c = __builtin_nontemporal_load(&adj4[i + 2 * stride]);
        iv4 d = __builtin_nontemporal_load(&adj4[i + 3 * stride]);
        emit_hits(a, i, deg, slots);
        emit_hits(b, i + stride, deg, slots);
        a = c; b = d; i += 2 * stride;
    }
    emit_hits(a, i, deg, slots);
    emit_hits(b, i + stride, deg, slots);
}

// ---------- kernel 2: fused SAGE layer (mean-agg + Wt GEMM + bias (+ReLU)) ----
// 32 nodes/block, 512 blocks. Gather: 8 threads/node x 4 float4; int4 index
// load gives 4 edges -> 16 independent row loads in flight per lane.
// GEMM: NPT=4 -> wave's 128KB Wt stream serves 8 nodes (W is L2-resident).
// LDS z[32][264] floats: float4 slots [0,32)=agg, [32,64)=self, 2 pad.
template <int FOUT, bool RELU>
__global__ __launch_bounds__(256) void k_layer(
    const float4* __restrict__ hin,    // [NN][32] float4
    float* __restrict__ hout,          // [NN][FOUT]
    const int* __restrict__ slots, const int* __restrict__ deg,
    const float4* __restrict__ Wt4,    // [256][FOUT/4]
    const float* __restrict__ bias)    // [FOUT]
{
    constexpr int S4 = 66;             // float4 stride per node row
    __shared__ float4 z[32 * S4];
    const int tid = threadIdx.x;
    const int nodeBase = blockIdx.x * 32;

    // stage self rows: 1024 float4s, coalesced (32 consecutive tids = one row)
    #pragma unroll
    for (int r = 0; r < 4; ++r) {
        int g = tid + 256 * r;
        int n = g >> 5, j = g & 31;
        z[n * S4 + 32 + j] = hin[(nodeBase + n) * 32 + j];
    }

    // mean aggregation: 8-thread cluster per node, 4 float4s/thread,
    // int4 index loads + 4-row unroll
    {
        const int nl = tid >> 3;       // 0..31 node-local
        const int q = tid & 7;         // 0..7
        const int node = nodeBase + nl;
        const int d = deg[node];
        const int dc = d < SLOTC ? d : SLOTC;
        const int* el = slots + node * SLOTC;   // 256B-aligned
        float4 acc[4];
        #pragma unroll
        for (int k = 0; k < 4; ++k) acc[k] = make_float4(0.f, 0.f, 0.f, 0.f);
        int e = 0;
        for (; e + 4 <= dc; e += 4) {
            int4 s4 = *(const int4*)(el + e);
            const float4* r0 = hin + s4.x * 32;
            const float4* r1 = hin + s4.y * 32;
            const float4* r2 = hin + s4.z * 32;
            const float4* r3 = hin + s4.w * 32;
            #pragma unroll
            for (int k = 0; k < 4; ++k) {
                float4 v0 = r0[q + 8 * k];
                float4 v1 = r1[q + 8 * k];
                float4 v2 = r2[q + 8 * k];
                float4 v3 = r3[q + 8 * k];
                acc[k].x += (v0.x + v1.x) + (v2.x + v3.x);
                acc[k].y += (v0.y + v1.y) + (v2.y + v3.y);
                acc[k].z += (v0.z + v1.z) + (v2.z + v3.z);
                acc[k].w += (v0.w + v1.w) + (v2.w + v3.w);
            }
        }
        for (; e < dc; ++e) {
            const float4* r0 = hin + el[e] * 32;
            #pragma unroll
            for (int k = 0; k < 4; ++k) {
                float4 va = r0[q + 8 * k];
                acc[k].x += va.x; acc[k].y += va.y;
                acc[k].z += va.z; acc[k].w += va.w;
            }
        }
        const float di = d > 0 ? 1.0f / (float)d : 0.0f;
        #pragma unroll
        for (int k = 0; k < 4; ++k) {
            acc[k].x *= di; acc[k].y *= di; acc[k].z *= di; acc[k].w *= di;
            z[nl * S4 + q + 8 * k] = acc[k];
        }
    }
    __syncthreads();

    // GEMM: out[32 x FOUT] = [agg|self][32 x 256] @ Wt + b
    constexpr int TO = FOUT / 4;       // 32 or 16
    constexpr int TN = 256 / TO;       // 8 or 16
    constexpr int NPT = 32 / TN;       // 4 or 2
    const int to = tid % TO;
    const int tn = tid / TO;

    float4 acc[NPT];
    #pragma unroll
    for (int m = 0; m < NPT; ++m) acc[m] = make_float4(0.f, 0.f, 0.f, 0.f);

    #pragma unroll 2
    for (int k4 = 0; k4 < 64; ++k4) {
        // Wt rows 4k4..4k4+3 at float4-col `to`: contiguous across lanes
        float4 w0 = Wt4[(4 * k4 + 0) * TO + to];
        float4 w1 = Wt4[(4 * k4 + 1) * TO + to];
        float4 w2 = Wt4[(4 * k4 + 2) * TO + to];
        float4 w3 = Wt4[(4 * k4 + 3) * TO + to];
        #pragma unroll
        for (int m = 0; m < NPT; ++m) {
            float4 a = z[(tn * NPT + m) * S4 + k4];   // ks 4k4..4k4+3
            acc[m].x += a.x * w0.x + a.y * w1.x + a.z * w2.x + a.w * w3.x;
            acc[m].y += a.x * w0.y + a.y * w1.y + a.z * w2.y + a.w * w3.y;
            acc[m].z += a.x * w0.z + a.y * w1.z + a.z * w2.z + a.w * w3.z;
            acc[m].w += a.x * w0.w + a.y * w1.w + a.z * w2.w + a.w * w3.w;
        }
    }

    // epilogue: +bias, optional ReLU, coalesced float4 store
    const float4 bb = ((const float4*)bias)[to];
    #pragma unroll
    for (int m = 0; m < NPT; ++m) {
        float4 o;
        o.x = acc[m].x + bb.x; o.y = acc[m].y + bb.y;
        o.z = acc[m].z + bb.z; o.w = acc[m].w + bb.w;
        if (RELU) {
            o.x = fmaxf(o.x, 0.f); o.y = fmaxf(o.y, 0.f);
            o.z = fmaxf(o.z, 0.f); o.w = fmaxf(o.w, 0.f);
        }
        ((float4*)hout)[(nodeBase + tn * NPT + m) * TO + to] = o;
    }
}

extern "C" void kernel_launch(void* const* d_in, const int* in_sizes, int n_in,
                              void* d_out, int out_size, void* d_ws, size_t ws_size,
                              hipStream_t stream) {
    const float* x = (const float*)d_in[0];
    const iv4* adj4 = (const iv4*)d_in[1];
    const float* Wl0 = (const float*)d_in[2];
    const float* b0 = (const float*)d_in[3];
    const float* Wr0 = (const float*)d_in[4];
    const float* Wl1 = (const float*)d_in[5];
    const float* b1 = (const float*)d_in[6];
    const float* Wr1 = (const float*)d_in[7];
    const float* Wl2 = (const float*)d_in[8];
    const float* b2 = (const float*)d_in[9];
    const float* Wr2 = (const float*)d_in[10];

    char* ws = (char*)d_ws;
    int* deg = (int*)(ws + OFF_DEG);
    int* slots = (int*)(ws + OFF_SLOT);
    float* wt0 = (float*)(ws + OFF_WT0);
    float* wt1 = (float*)(ws + OFF_WT1);
    float* wt2 = (float*)(ws + OFF_WT2);
    float* h1 = (float*)(ws + OFF_H1);
    float* h2 = (float*)(ws + OFF_H2);

    // 0) transpose weights + zero deg (precedes k_count on this stream)
    k_wt<<<320, 256, 0, stream>>>(Wl0, Wr0, Wl1, Wr1, Wl2, Wr2,
                                  wt0, wt1, wt2, deg);
    // 1) scan adj (the 1.07 GB roofline read), scatter edges into slots
    k_count<<<2048, 256, 0, stream>>>(adj4, deg, slots);
    // 2) three fused SAGE layers
    k_layer<128, true><<<NN / 32, 256, 0, stream>>>(
        (const float4*)x, h1, slots, deg, (const float4*)wt0, b0);
    k_layer<128, true><<<NN / 32, 256, 0, stream>>>(
        (const float4*)h1, h2, slots, deg, (const float4*)wt1, b1);
    k_layer<64, false><<<NN / 32, 256, 0, stream>>>(
        (const float4*)h2, (float*)d_out, slots, deg, (const float4*)wt2, b2);
}